// Round 3
// baseline (976.389 us; speedup 1.0000x reference)
//
#include <hip/hip_runtime.h>
#include <hip/hip_fp16.h>

// ---------------------------------------------------------------------------
// ConstraintLoss:
//   values = sigmoid(pred)                                  [n_vars]
//   ax = segment_sum(coeff * values[var_idx], constr_idx)   [n_constrs]
//   viol[c] = sense==1 ? relu(ax-b) : sense==2 ? relu(b-ax) : sense==3 ? |ax-b| : 0
//   out = mean(viol)
//
// Round-3: round 2's two-phase binning took 1152 -> 587 us. Remaining costs:
//   (a) binning FETCH 839 MB = 240 streams + ~160 write-allocate + ~440 gather
//       (fp32 values = 8 MB > 4 MB XCD L2 -> near-100% miss).
//   (b) phase 2 at 64 KiB LDS = 2 blocks/CU, dependent load->ds_add chain.
// Fixes: fp16 values (4 MB, fits XCD L2; scalar-mean output error ~1e-6),
// non-temporal stream loads / bin stores to keep values resident, BW=8192
// buckets (32 KiB LDS, 4 blocks/CU, 2x blocks), unrolled phase-2 loop,
// cursor counters padded to one cache line each.
// ---------------------------------------------------------------------------

#define BW_LOG2 13
#define BW (1 << BW_LOG2)            // 8192 constraints/bucket = 32 KiB LDS
#define MAXNB 128
#define NREP 8
#define P1_THREADS 512
#define VPT 8
#define P1_CHUNK (P1_THREADS * VPT)  // 4096 nnz per phase-1 block
#define CUR_PAD 16                   // one 64B line per cursor counter

typedef int   v4i __attribute__((ext_vector_type(4)));
typedef float v4f __attribute__((ext_vector_type(4)));

__global__ void sigmoid_kernel(const float* __restrict__ pred,
                               __half* __restrict__ values, int n) {
    int i = blockIdx.x * blockDim.x + threadIdx.x;
    int stride = gridDim.x * blockDim.x;
    int n4 = n >> 2;
    const v4f* p4 = (const v4f*)pred;
    uint2* o = (uint2*)values;  // 4 halves = 8B
    for (int j = i; j < n4; j += stride) {
        v4f p = p4[j];
        float a0 = 1.0f / (1.0f + __expf(-p.x));
        float a1 = 1.0f / (1.0f + __expf(-p.y));
        float a2 = 1.0f / (1.0f + __expf(-p.z));
        float a3 = 1.0f / (1.0f + __expf(-p.w));
        unsigned lo = ((unsigned)__half_as_ushort(__float2half_rn(a1)) << 16) |
                      (unsigned)__half_as_ushort(__float2half_rn(a0));
        unsigned hi = ((unsigned)__half_as_ushort(__float2half_rn(a3)) << 16) |
                      (unsigned)__half_as_ushort(__float2half_rn(a2));
        o[j] = make_uint2(lo, hi);
    }
    for (int j = (n4 << 2) + i; j < n; j += stride)
        values[j] = __float2half_rn(1.0f / (1.0f + __expf(-pred[j])));
}

// ---------------- phase 1: bin {cidx, val} into per-bucket regions ----------
__global__ __launch_bounds__(P1_THREADS) void binning_kernel(
    const int* __restrict__ cidx, const int* __restrict__ vidx,
    const float* __restrict__ coeff, const __half* __restrict__ values,
    unsigned long long* __restrict__ bins, int* __restrict__ cursor,
    float* __restrict__ ovf, int nnz, int nb, int cap) {
    __shared__ int hist[MAXNB];
    __shared__ int sbase[MAXNB];
    const int tid = threadIdx.x;
    const long long start = (long long)blockIdx.x * P1_CHUNK;

    for (int i = tid; i < nb; i += P1_THREADS) hist[i] = 0;
    __syncthreads();

    unsigned packed[VPT];  // cidx (20b) | local offset (12b, < 4096)
    float val[VPT];

    if (start + P1_CHUNK <= (long long)nnz) {
        const v4i* c4 = (const v4i*)(cidx + start);
        const v4i* v4 = (const v4i*)(vidx + start);
        const v4f* w4 = (const v4f*)(coeff + start);
#pragma unroll
        for (int k = 0; k < VPT / 4; ++k) {
            int g = k * P1_THREADS + tid;
            v4i c = __builtin_nontemporal_load(&c4[g]);
            v4i v = __builtin_nontemporal_load(&v4[g]);
            v4f w = __builtin_nontemporal_load(&w4[g]);
            float x0 = w.x * __half2float(values[v.x]);
            float x1 = w.y * __half2float(values[v.y]);
            float x2 = w.z * __half2float(values[v.z]);
            float x3 = w.w * __half2float(values[v.w]);
            int l0 = atomicAdd(&hist[c.x >> BW_LOG2], 1);
            int l1 = atomicAdd(&hist[c.y >> BW_LOG2], 1);
            int l2 = atomicAdd(&hist[c.z >> BW_LOG2], 1);
            int l3 = atomicAdd(&hist[c.w >> BW_LOG2], 1);
            packed[k * 4 + 0] = (unsigned)c.x | ((unsigned)l0 << 20);
            packed[k * 4 + 1] = (unsigned)c.y | ((unsigned)l1 << 20);
            packed[k * 4 + 2] = (unsigned)c.z | ((unsigned)l2 << 20);
            packed[k * 4 + 3] = (unsigned)c.w | ((unsigned)l3 << 20);
            val[k * 4 + 0] = x0;
            val[k * 4 + 1] = x1;
            val[k * 4 + 2] = x2;
            val[k * 4 + 3] = x3;
        }
    } else {
        // guarded scalar tail block
#pragma unroll
        for (int k = 0; k < VPT; ++k) {
            long long idx = start + (long long)k * P1_THREADS + tid;
            if (idx < nnz) {
                int c = cidx[idx];
                float x = coeff[idx] * __half2float(values[vidx[idx]]);
                int l = atomicAdd(&hist[c >> BW_LOG2], 1);
                packed[k] = (unsigned)c | ((unsigned)l << 20);
                val[k] = x;
            } else {
                packed[k] = 0xFFFFFFFFu;  // unreachable for valid c (< 2^20-1)
            }
        }
    }
    __syncthreads();
    for (int i = tid; i < nb; i += P1_THREADS)
        sbase[i] = atomicAdd(&cursor[i * CUR_PAD], hist[i]);
    __syncthreads();
#pragma unroll
    for (int k = 0; k < VPT; ++k) {
        if (packed[k] == 0xFFFFFFFFu) continue;
        unsigned c = packed[k] & 0xFFFFFu;
        int loc = (int)(packed[k] >> 20);
        int b = (int)(c >> BW_LOG2);
        int pos = sbase[b] + loc;
        if (pos < cap) {
            unsigned long long e = (unsigned long long)c |
                ((unsigned long long)__float_as_uint(val[k]) << 32);
            __builtin_nontemporal_store(e, &bins[(size_t)b * cap + pos]);
        } else {
            atomicAdd(&ovf[c], val[k]);  // never taken for uniform inputs
        }
    }
}

// ------------- phase 2: per-(bucket, slice) LDS accumulation ---------------
__global__ __launch_bounds__(512) void bucket_accum_kernel(
    const unsigned long long* __restrict__ bins, const int* __restrict__ cursor,
    float* __restrict__ rep, int nb, int cap, int n_constrs, int rep_stride) {
    __shared__ float acc[BW];  // 32 KiB
    const int tid = threadIdx.x;
    const int b = blockIdx.x >> 3;  // NREP == 8
    const int r = blockIdx.x & 7;

    v4f* a4 = (v4f*)acc;
    v4f zero = {0.0f, 0.0f, 0.0f, 0.0f};
#pragma unroll
    for (int k = 0; k < BW / 4 / 512; ++k)
        a4[k * 512 + tid] = zero;
    __syncthreads();

    int cnt = cursor[b * CUR_PAD];
    if (cnt > cap) cnt = cap;
    int begin = (int)((long long)cnt * r / NREP);
    int end = (int)((long long)cnt * (r + 1) / NREP);
    const unsigned long long* mb = bins + (size_t)b * cap;
    const unsigned cbase = (unsigned)b << BW_LOG2;

    int i = begin + tid;
    for (; i + 512 * 3 < end; i += 512 * 4) {
        unsigned long long e0 = mb[i];
        unsigned long long e1 = mb[i + 512];
        unsigned long long e2 = mb[i + 1024];
        unsigned long long e3 = mb[i + 1536];
        atomicAdd(&acc[((unsigned)e0 & 0xFFFFFu) - cbase], __uint_as_float((unsigned)(e0 >> 32)));
        atomicAdd(&acc[((unsigned)e1 & 0xFFFFFu) - cbase], __uint_as_float((unsigned)(e1 >> 32)));
        atomicAdd(&acc[((unsigned)e2 & 0xFFFFFu) - cbase], __uint_as_float((unsigned)(e2 >> 32)));
        atomicAdd(&acc[((unsigned)e3 & 0xFFFFFu) - cbase], __uint_as_float((unsigned)(e3 >> 32)));
    }
    for (; i < end; i += 512) {
        unsigned long long e = mb[i];
        atomicAdd(&acc[((unsigned)e & 0xFFFFFu) - cbase], __uint_as_float((unsigned)(e >> 32)));
    }
    __syncthreads();

    float* out = rep + (size_t)r * rep_stride + cbase;
    int lim = n_constrs - (int)cbase;
    if (lim >= BW) {
        v4f* o4 = (v4f*)out;
#pragma unroll
        for (int k = 0; k < BW / 4 / 512; ++k)
            o4[k * 512 + tid] = a4[k * 512 + tid];
    } else {
        for (int j = tid; j < lim; j += 512) out[j] = acc[j];
    }
}

// ---------------- violation + mean reduction over NR strides ----------------
template <int NR>
__global__ void violation_reduce_kernel(const float* __restrict__ rep,
                                        const float* __restrict__ rhs,
                                        const int* __restrict__ sense,
                                        float* __restrict__ out,
                                        int n, int rep_stride, float inv_n) {
    int i = blockIdx.x * blockDim.x + threadIdx.x;
    int stride = gridDim.x * blockDim.x;
    float acc = 0.0f;
    int n4 = n >> 2;
    const float4* r4 = (const float4*)rhs;
    const int4* s4 = (const int4*)sense;
    for (int j = i; j < n4; j += stride) {
        float4 a = make_float4(0.0f, 0.0f, 0.0f, 0.0f);
#pragma unroll
        for (int r = 0; r < NR; ++r) {
            const float4* a4 = (const float4*)(rep + (size_t)r * (size_t)rep_stride);
            float4 t = a4[j];
            a.x += t.x; a.y += t.y; a.z += t.z; a.w += t.w;
        }
        float4 rr = r4[j];
        int4 s = s4[j];
        float d;
        d = a.x - rr.x;
        acc += (s.x == 1) ? fmaxf(d, 0.0f) : (s.x == 2) ? fmaxf(-d, 0.0f) : (s.x == 3) ? fabsf(d) : 0.0f;
        d = a.y - rr.y;
        acc += (s.y == 1) ? fmaxf(d, 0.0f) : (s.y == 2) ? fmaxf(-d, 0.0f) : (s.y == 3) ? fabsf(d) : 0.0f;
        d = a.z - rr.z;
        acc += (s.z == 1) ? fmaxf(d, 0.0f) : (s.z == 2) ? fmaxf(-d, 0.0f) : (s.z == 3) ? fabsf(d) : 0.0f;
        d = a.w - rr.w;
        acc += (s.w == 1) ? fmaxf(d, 0.0f) : (s.w == 2) ? fmaxf(-d, 0.0f) : (s.w == 3) ? fabsf(d) : 0.0f;
    }
    for (int j = (n4 << 2) + i; j < n; j += stride) {
        float a = 0.0f;
#pragma unroll
        for (int r = 0; r < NR; ++r) a += rep[(size_t)r * (size_t)rep_stride + j];
        float d = a - rhs[j];
        int s = sense[j];
        acc += (s == 1) ? fmaxf(d, 0.0f) : (s == 2) ? fmaxf(-d, 0.0f) : (s == 3) ? fabsf(d) : 0.0f;
    }

    for (int off = 32; off > 0; off >>= 1)
        acc += __shfl_down(acc, off, 64);

    __shared__ float lds[8];
    int lane = threadIdx.x & 63;
    int wave = threadIdx.x >> 6;
    if (lane == 0) lds[wave] = acc;
    __syncthreads();
    if (wave == 0) {
        int nwaves = blockDim.x >> 6;
        float b = (lane < nwaves) ? lds[lane] : 0.0f;
        for (int off = 4; off > 0; off >>= 1)
            b += __shfl_down(b, off, 64);
        if (lane == 0) atomicAdd(out, b * inv_n);
    }
}

// ---------------- fallback (small workspace): atomic scatter ----------------
__global__ void scatter_kernel(const int* __restrict__ cidx,
                               const int* __restrict__ vidx,
                               const float* __restrict__ coeff,
                               const __half* __restrict__ values,
                               float* __restrict__ ax, int nnz) {
    int i = blockIdx.x * blockDim.x + threadIdx.x;
    int stride = gridDim.x * blockDim.x;
    int n4 = nnz >> 2;
    const int4* c4 = (const int4*)cidx;
    const int4* v4 = (const int4*)vidx;
    const float4* w4 = (const float4*)coeff;
    for (int j = i; j < n4; j += stride) {
        int4 c = c4[j];
        int4 v = v4[j];
        float4 w = w4[j];
        atomicAdd(&ax[c.x], w.x * __half2float(values[v.x]));
        atomicAdd(&ax[c.y], w.y * __half2float(values[v.y]));
        atomicAdd(&ax[c.z], w.z * __half2float(values[v.z]));
        atomicAdd(&ax[c.w], w.w * __half2float(values[v.w]));
    }
    for (int j = (n4 << 2) + i; j < nnz; j += stride)
        atomicAdd(&ax[cidx[j]], coeff[j] * __half2float(values[vidx[j]]));
}

extern "C" void kernel_launch(void* const* d_in, const int* in_sizes, int n_in,
                              void* d_out, int out_size, void* d_ws, size_t ws_size,
                              hipStream_t stream) {
    const float* pred  = (const float*)d_in[0];
    const int*   cidx  = (const int*)d_in[1];
    const int*   vidx  = (const int*)d_in[2];
    const float* coeff = (const float*)d_in[3];
    const float* rhs   = (const float*)d_in[4];
    const int*   sense = (const int*)d_in[5];

    const int n_vars    = in_sizes[0];
    const int nnz       = in_sizes[1];
    const int n_constrs = in_sizes[4];

    const int rep_stride = (n_constrs + 15) & ~15;
    const size_t vh_bytes = ((size_t)n_vars * 2 + 255) & ~(size_t)255;

    __half* values = (__half*)d_ws;
    float* rep = (float*)((char*)d_ws + vh_bytes);        // (NREP+1) * rep_stride
    float* ovf = rep + (size_t)NREP * rep_stride;         // 9th stride = overflow
    int* cursor = (int*)(ovf + rep_stride);               // MAXNB * CUR_PAD ints
    unsigned long long* bins =
        (unsigned long long*)(cursor + MAXNB * CUR_PAD);

    const int nb = (n_constrs + BW - 1) >> BW_LOG2;
    long long cap_ll = (long long)nnz * BW / n_constrs
                     + (long long)nnz / ((long long)(nb > 0 ? nb : 1) * 32) + 2048;
    const int cap = (int)cap_ll;
    const size_t need = vh_bytes
                      + (size_t)(NREP + 1) * rep_stride * 4
                      + (size_t)MAXNB * CUR_PAD * 4
                      + (size_t)nb * (size_t)cap * 8;
    const bool fast = (nb >= 1) && (nb <= MAXNB) && (n_constrs < (1 << 20)) &&
                      (nnz > P1_CHUNK) && (ws_size >= need);

    hipMemsetAsync(d_out, 0, sizeof(float), stream);

    {
        int threads = 256;
        int work = n_vars >> 2;
        int blocks = (work + threads - 1) / threads;
        if (blocks < 1) blocks = 1;
        if (blocks > 2048) blocks = 2048;
        sigmoid_kernel<<<blocks, threads, 0, stream>>>(pred, values, n_vars);
    }

    if (fast) {
        hipMemsetAsync(cursor, 0, (size_t)MAXNB * CUR_PAD * sizeof(int), stream);
        hipMemsetAsync(ovf, 0, (size_t)rep_stride * sizeof(float), stream);

        int p1_blocks = (int)(((long long)nnz + P1_CHUNK - 1) / P1_CHUNK);
        binning_kernel<<<p1_blocks, P1_THREADS, 0, stream>>>(
            cidx, vidx, coeff, values, bins, cursor, ovf, nnz, nb, cap);

        bucket_accum_kernel<<<nb * NREP, 512, 0, stream>>>(
            bins, cursor, rep, nb, cap, n_constrs, rep_stride);

        int threads = 256;
        int work = n_constrs >> 2;
        int blocks = (work + threads - 1) / threads;
        if (blocks > 4096) blocks = 4096;
        violation_reduce_kernel<NREP + 1><<<blocks, threads, 0, stream>>>(
            rep, rhs, sense, (float*)d_out, n_constrs, rep_stride,
            1.0f / (float)n_constrs);
    } else {
        hipMemsetAsync(rep, 0, (size_t)n_constrs * sizeof(float), stream);
        int threads = 256;
        int work = nnz >> 2;
        int blocks = (work + threads - 1) / threads;
        if (blocks > 8192) blocks = 8192;
        scatter_kernel<<<blocks, threads, 0, stream>>>(
            cidx, vidx, coeff, values, rep, nnz);

        int vthreads = 256;
        int vwork = n_constrs >> 2;
        int vblocks = (vwork + vthreads - 1) / vthreads;
        if (vblocks > 4096) vblocks = 4096;
        violation_reduce_kernel<1><<<vblocks, vthreads, 0, stream>>>(
            rep, rhs, sense, (float*)d_out, n_constrs, n_constrs,
            1.0f / (float)n_constrs);
    }
}

// Round 5
// 539.568 us; speedup vs baseline: 1.8096x; 1.8096x over previous
//
#include <hip/hip_runtime.h>
#include <hip/hip_fp16.h>

// ---------------------------------------------------------------------------
// ConstraintLoss:
//   values = sigmoid(pred)                                  [n_vars]
//   ax = segment_sum(coeff * values[var_idx], constr_idx)   [n_constrs]
//   viol[c] = sense==1 ? relu(ax-b) : sense==2 ? relu(b-ax) : sense==3 ? |ax-b| : 0
//   out = mean(viol)
//
// Round-5 == round-4 resubmitted (round-4 bench was an infra failure, not a
// kernel failure). Round 3 proved (a) fp16 values + NT stream loads make the
// gather ~free (binning FETCH 839 -> 214 MB), and (b) NT stores on the 8B bin
// entries bypass L2 write-combining and serialize memory-side (WRITE 171 ->
// 888 MB, dur 293 -> 690 us). This round keeps (a) and reverts (b): plain
// stores to the per-block-contiguous bucket ranges let L2 merge them into
// full lines (round 2 measured WRITE == bins size exactly).
// ---------------------------------------------------------------------------

#define BW_LOG2 13
#define BW (1 << BW_LOG2)            // 8192 constraints/bucket = 32 KiB LDS
#define MAXNB 128
#define NREP 8
#define P1_THREADS 512
#define VPT 8
#define P1_CHUNK (P1_THREADS * VPT)  // 4096 nnz per phase-1 block
#define CUR_PAD 16                   // one 64B line per cursor counter

typedef int   v4i __attribute__((ext_vector_type(4)));
typedef float v4f __attribute__((ext_vector_type(4)));

__global__ void sigmoid_kernel(const float* __restrict__ pred,
                               __half* __restrict__ values, int n) {
    int i = blockIdx.x * blockDim.x + threadIdx.x;
    int stride = gridDim.x * blockDim.x;
    int n4 = n >> 2;
    const v4f* p4 = (const v4f*)pred;
    uint2* o = (uint2*)values;  // 4 halves = 8B
    for (int j = i; j < n4; j += stride) {
        v4f p = p4[j];
        float a0 = 1.0f / (1.0f + __expf(-p.x));
        float a1 = 1.0f / (1.0f + __expf(-p.y));
        float a2 = 1.0f / (1.0f + __expf(-p.z));
        float a3 = 1.0f / (1.0f + __expf(-p.w));
        unsigned lo = ((unsigned)__half_as_ushort(__float2half_rn(a1)) << 16) |
                      (unsigned)__half_as_ushort(__float2half_rn(a0));
        unsigned hi = ((unsigned)__half_as_ushort(__float2half_rn(a3)) << 16) |
                      (unsigned)__half_as_ushort(__float2half_rn(a2));
        o[j] = make_uint2(lo, hi);
    }
    for (int j = (n4 << 2) + i; j < n; j += stride)
        values[j] = __float2half_rn(1.0f / (1.0f + __expf(-pred[j])));
}

// ---------------- phase 1: bin {cidx, val} into per-bucket regions ----------
__global__ __launch_bounds__(P1_THREADS) void binning_kernel(
    const int* __restrict__ cidx, const int* __restrict__ vidx,
    const float* __restrict__ coeff, const __half* __restrict__ values,
    unsigned long long* __restrict__ bins, int* __restrict__ cursor,
    float* __restrict__ ovf, int nnz, int nb, int cap) {
    __shared__ int hist[MAXNB];
    __shared__ int sbase[MAXNB];
    const int tid = threadIdx.x;
    const long long start = (long long)blockIdx.x * P1_CHUNK;

    for (int i = tid; i < nb; i += P1_THREADS) hist[i] = 0;
    __syncthreads();

    unsigned packed[VPT];  // cidx (20b) | local offset (12b, < 4096)
    float val[VPT];

    if (start + P1_CHUNK <= (long long)nnz) {
        const v4i* c4 = (const v4i*)(cidx + start);
        const v4i* v4 = (const v4i*)(vidx + start);
        const v4f* w4 = (const v4f*)(coeff + start);
#pragma unroll
        for (int k = 0; k < VPT / 4; ++k) {
            int g = k * P1_THREADS + tid;
            v4i c = __builtin_nontemporal_load(&c4[g]);
            v4i v = __builtin_nontemporal_load(&v4[g]);
            v4f w = __builtin_nontemporal_load(&w4[g]);
            float x0 = w.x * __half2float(values[v.x]);
            float x1 = w.y * __half2float(values[v.y]);
            float x2 = w.z * __half2float(values[v.z]);
            float x3 = w.w * __half2float(values[v.w]);
            int l0 = atomicAdd(&hist[c.x >> BW_LOG2], 1);
            int l1 = atomicAdd(&hist[c.y >> BW_LOG2], 1);
            int l2 = atomicAdd(&hist[c.z >> BW_LOG2], 1);
            int l3 = atomicAdd(&hist[c.w >> BW_LOG2], 1);
            packed[k * 4 + 0] = (unsigned)c.x | ((unsigned)l0 << 20);
            packed[k * 4 + 1] = (unsigned)c.y | ((unsigned)l1 << 20);
            packed[k * 4 + 2] = (unsigned)c.z | ((unsigned)l2 << 20);
            packed[k * 4 + 3] = (unsigned)c.w | ((unsigned)l3 << 20);
            val[k * 4 + 0] = x0;
            val[k * 4 + 1] = x1;
            val[k * 4 + 2] = x2;
            val[k * 4 + 3] = x3;
        }
    } else {
        // guarded scalar tail block
#pragma unroll
        for (int k = 0; k < VPT; ++k) {
            long long idx = start + (long long)k * P1_THREADS + tid;
            if (idx < nnz) {
                int c = cidx[idx];
                float x = coeff[idx] * __half2float(values[vidx[idx]]);
                int l = atomicAdd(&hist[c >> BW_LOG2], 1);
                packed[k] = (unsigned)c | ((unsigned)l << 20);
                val[k] = x;
            } else {
                packed[k] = 0xFFFFFFFFu;  // unreachable for valid c (< 2^20-1)
            }
        }
    }
    __syncthreads();
    for (int i = tid; i < nb; i += P1_THREADS)
        sbase[i] = atomicAdd(&cursor[i * CUR_PAD], hist[i]);
    __syncthreads();
#pragma unroll
    for (int k = 0; k < VPT; ++k) {
        if (packed[k] == 0xFFFFFFFFu) continue;
        unsigned c = packed[k] & 0xFFFFFu;
        int loc = (int)(packed[k] >> 20);
        int b = (int)(c >> BW_LOG2);
        int pos = sbase[b] + loc;
        if (pos < cap) {
            unsigned long long e = (unsigned long long)c |
                ((unsigned long long)__float_as_uint(val[k]) << 32);
            // PLAIN store: per-block bucket ranges are contiguous, L2 merges
            // them into full lines (NT store here was the round-3 regression).
            bins[(size_t)b * cap + pos] = e;
        } else {
            atomicAdd(&ovf[c], val[k]);  // never taken for uniform inputs
        }
    }
}

// ------------- phase 2: per-(bucket, slice) LDS accumulation ---------------
__global__ __launch_bounds__(512) void bucket_accum_kernel(
    const unsigned long long* __restrict__ bins, const int* __restrict__ cursor,
    float* __restrict__ rep, int nb, int cap, int n_constrs, int rep_stride) {
    __shared__ float acc[BW];  // 32 KiB
    const int tid = threadIdx.x;
    const int b = blockIdx.x >> 3;  // NREP == 8
    const int r = blockIdx.x & 7;

    v4f* a4 = (v4f*)acc;
    v4f zero = {0.0f, 0.0f, 0.0f, 0.0f};
#pragma unroll
    for (int k = 0; k < BW / 4 / 512; ++k)
        a4[k * 512 + tid] = zero;
    __syncthreads();

    int cnt = cursor[b * CUR_PAD];
    if (cnt > cap) cnt = cap;
    int begin = (int)((long long)cnt * r / NREP);
    int end = (int)((long long)cnt * (r + 1) / NREP);
    const unsigned long long* mb = bins + (size_t)b * cap;
    const unsigned cbase = (unsigned)b << BW_LOG2;

    int i = begin + tid;
    for (; i + 512 * 3 < end; i += 512 * 4) {
        unsigned long long e0 = mb[i];
        unsigned long long e1 = mb[i + 512];
        unsigned long long e2 = mb[i + 1024];
        unsigned long long e3 = mb[i + 1536];
        atomicAdd(&acc[((unsigned)e0 & 0xFFFFFu) - cbase], __uint_as_float((unsigned)(e0 >> 32)));
        atomicAdd(&acc[((unsigned)e1 & 0xFFFFFu) - cbase], __uint_as_float((unsigned)(e1 >> 32)));
        atomicAdd(&acc[((unsigned)e2 & 0xFFFFFu) - cbase], __uint_as_float((unsigned)(e2 >> 32)));
        atomicAdd(&acc[((unsigned)e3 & 0xFFFFFu) - cbase], __uint_as_float((unsigned)(e3 >> 32)));
    }
    for (; i < end; i += 512) {
        unsigned long long e = mb[i];
        atomicAdd(&acc[((unsigned)e & 0xFFFFFu) - cbase], __uint_as_float((unsigned)(e >> 32)));
    }
    __syncthreads();

    float* out = rep + (size_t)r * rep_stride + cbase;
    int lim = n_constrs - (int)cbase;
    if (lim >= BW) {
        v4f* o4 = (v4f*)out;
#pragma unroll
        for (int k = 0; k < BW / 4 / 512; ++k)
            o4[k * 512 + tid] = a4[k * 512 + tid];
    } else {
        for (int j = tid; j < lim; j += 512) out[j] = acc[j];
    }
}

// ---------------- violation + mean reduction over NR strides ----------------
template <int NR>
__global__ void violation_reduce_kernel(const float* __restrict__ rep,
                                        const float* __restrict__ rhs,
                                        const int* __restrict__ sense,
                                        float* __restrict__ out,
                                        int n, int rep_stride, float inv_n) {
    int i = blockIdx.x * blockDim.x + threadIdx.x;
    int stride = gridDim.x * blockDim.x;
    float acc = 0.0f;
    int n4 = n >> 2;
    const float4* r4 = (const float4*)rhs;
    const int4* s4 = (const int4*)sense;
    for (int j = i; j < n4; j += stride) {
        float4 a = make_float4(0.0f, 0.0f, 0.0f, 0.0f);
#pragma unroll
        for (int r = 0; r < NR; ++r) {
            const float4* a4 = (const float4*)(rep + (size_t)r * (size_t)rep_stride);
            float4 t = a4[j];
            a.x += t.x; a.y += t.y; a.z += t.z; a.w += t.w;
        }
        float4 rr = r4[j];
        int4 s = s4[j];
        float d;
        d = a.x - rr.x;
        acc += (s.x == 1) ? fmaxf(d, 0.0f) : (s.x == 2) ? fmaxf(-d, 0.0f) : (s.x == 3) ? fabsf(d) : 0.0f;
        d = a.y - rr.y;
        acc += (s.y == 1) ? fmaxf(d, 0.0f) : (s.y == 2) ? fmaxf(-d, 0.0f) : (s.y == 3) ? fabsf(d) : 0.0f;
        d = a.z - rr.z;
        acc += (s.z == 1) ? fmaxf(d, 0.0f) : (s.z == 2) ? fmaxf(-d, 0.0f) : (s.z == 3) ? fabsf(d) : 0.0f;
        d = a.w - rr.w;
        acc += (s.w == 1) ? fmaxf(d, 0.0f) : (s.w == 2) ? fmaxf(-d, 0.0f) : (s.w == 3) ? fabsf(d) : 0.0f;
    }
    for (int j = (n4 << 2) + i; j < n; j += stride) {
        float a = 0.0f;
#pragma unroll
        for (int r = 0; r < NR; ++r) a += rep[(size_t)r * (size_t)rep_stride + j];
        float d = a - rhs[j];
        int s = sense[j];
        acc += (s == 1) ? fmaxf(d, 0.0f) : (s == 2) ? fmaxf(-d, 0.0f) : (s == 3) ? fabsf(d) : 0.0f;
    }

    for (int off = 32; off > 0; off >>= 1)
        acc += __shfl_down(acc, off, 64);

    __shared__ float lds[8];
    int lane = threadIdx.x & 63;
    int wave = threadIdx.x >> 6;
    if (lane == 0) lds[wave] = acc;
    __syncthreads();
    if (wave == 0) {
        int nwaves = blockDim.x >> 6;
        float b = (lane < nwaves) ? lds[lane] : 0.0f;
        for (int off = 4; off > 0; off >>= 1)
            b += __shfl_down(b, off, 64);
        if (lane == 0) atomicAdd(out, b * inv_n);
    }
}

// ---------------- fallback (small workspace): atomic scatter ----------------
__global__ void scatter_kernel(const int* __restrict__ cidx,
                               const int* __restrict__ vidx,
                               const float* __restrict__ coeff,
                               const __half* __restrict__ values,
                               float* __restrict__ ax, int nnz) {
    int i = blockIdx.x * blockDim.x + threadIdx.x;
    int stride = gridDim.x * blockDim.x;
    int n4 = nnz >> 2;
    const int4* c4 = (const int4*)cidx;
    const int4* v4 = (const int4*)vidx;
    const float4* w4 = (const float4*)coeff;
    for (int j = i; j < n4; j += stride) {
        int4 c = c4[j];
        int4 v = v4[j];
        float4 w = w4[j];
        atomicAdd(&ax[c.x], w.x * __half2float(values[v.x]));
        atomicAdd(&ax[c.y], w.y * __half2float(values[v.y]));
        atomicAdd(&ax[c.z], w.z * __half2float(values[v.z]));
        atomicAdd(&ax[c.w], w.w * __half2float(values[v.w]));
    }
    for (int j = (n4 << 2) + i; j < nnz; j += stride)
        atomicAdd(&ax[cidx[j]], coeff[j] * __half2float(values[vidx[j]]));
}

extern "C" void kernel_launch(void* const* d_in, const int* in_sizes, int n_in,
                              void* d_out, int out_size, void* d_ws, size_t ws_size,
                              hipStream_t stream) {
    const float* pred  = (const float*)d_in[0];
    const int*   cidx  = (const int*)d_in[1];
    const int*   vidx  = (const int*)d_in[2];
    const float* coeff = (const float*)d_in[3];
    const float* rhs   = (const float*)d_in[4];
    const int*   sense = (const int*)d_in[5];

    const int n_vars    = in_sizes[0];
    const int nnz       = in_sizes[1];
    const int n_constrs = in_sizes[4];

    const int rep_stride = (n_constrs + 15) & ~15;
    const size_t vh_bytes = ((size_t)n_vars * 2 + 255) & ~(size_t)255;

    __half* values = (__half*)d_ws;
    float* rep = (float*)((char*)d_ws + vh_bytes);        // (NREP+1) * rep_stride
    float* ovf = rep + (size_t)NREP * rep_stride;         // 9th stride = overflow
    int* cursor = (int*)(ovf + rep_stride);               // MAXNB * CUR_PAD ints
    unsigned long long* bins =
        (unsigned long long*)(cursor + MAXNB * CUR_PAD);

    const int nb = (n_constrs + BW - 1) >> BW_LOG2;
    long long cap_ll = (long long)nnz * BW / n_constrs
                     + (long long)nnz / ((long long)(nb > 0 ? nb : 1) * 32) + 2048;
    const int cap = (int)cap_ll;
    const size_t need = vh_bytes
                      + (size_t)(NREP + 1) * rep_stride * 4
                      + (size_t)MAXNB * CUR_PAD * 4
                      + (size_t)nb * (size_t)cap * 8;
    const bool fast = (nb >= 1) && (nb <= MAXNB) && (n_constrs < (1 << 20)) &&
                      (nnz > P1_CHUNK) && (ws_size >= need);

    hipMemsetAsync(d_out, 0, sizeof(float), stream);

    {
        int threads = 256;
        int work = n_vars >> 2;
        int blocks = (work + threads - 1) / threads;
        if (blocks < 1) blocks = 1;
        if (blocks > 2048) blocks = 2048;
        sigmoid_kernel<<<blocks, threads, 0, stream>>>(pred, values, n_vars);
    }

    if (fast) {
        hipMemsetAsync(cursor, 0, (size_t)MAXNB * CUR_PAD * sizeof(int), stream);
        hipMemsetAsync(ovf, 0, (size_t)rep_stride * sizeof(float), stream);

        int p1_blocks = (int)(((long long)nnz + P1_CHUNK - 1) / P1_CHUNK);
        binning_kernel<<<p1_blocks, P1_THREADS, 0, stream>>>(
            cidx, vidx, coeff, values, bins, cursor, ovf, nnz, nb, cap);

        bucket_accum_kernel<<<nb * NREP, 512, 0, stream>>>(
            bins, cursor, rep, nb, cap, n_constrs, rep_stride);

        int threads = 256;
        int work = n_constrs >> 2;
        int blocks = (work + threads - 1) / threads;
        if (blocks > 4096) blocks = 4096;
        violation_reduce_kernel<NREP + 1><<<blocks, threads, 0, stream>>>(
            rep, rhs, sense, (float*)d_out, n_constrs, rep_stride,
            1.0f / (float)n_constrs);
    } else {
        hipMemsetAsync(rep, 0, (size_t)n_constrs * sizeof(float), stream);
        int threads = 256;
        int work = nnz >> 2;
        int blocks = (work + threads - 1) / threads;
        if (blocks > 8192) blocks = 8192;
        scatter_kernel<<<blocks, threads, 0, stream>>>(
            cidx, vidx, coeff, values, rep, nnz);

        int vthreads = 256;
        int vwork = n_constrs >> 2;
        int vblocks = (vwork + vthreads - 1) / vthreads;
        if (vblocks > 4096) vblocks = 4096;
        violation_reduce_kernel<1><<<vblocks, vthreads, 0, stream>>>(
            rep, rhs, sense, (float*)d_out, n_constrs, n_constrs,
            1.0f / (float)n_constrs);
    }
}

// Round 6
// 525.765 us; speedup vs baseline: 1.8571x; 1.0263x over previous
//
#include <hip/hip_runtime.h>
#include <hip/hip_fp16.h>

// ---------------------------------------------------------------------------
// ConstraintLoss:
//   values = sigmoid(pred)                                  [n_vars]
//   ax = segment_sum(coeff * values[var_idx], constr_idx)   [n_constrs]
//   viol[c] = sense==1 ? relu(ax-b) : sense==2 ? relu(b-ax) : sense==3 ? |ax-b| : 0
//   out = mean(viol)
//
// Round-6: binning traffic diet + phase-2/violation fusion.
//  - Bin entries shrink 8B -> 4B: {fp16 val | 12-bit local cidx}. fp16 values
//    already pass (absmax 0.0); product rounding adds ~1e-6 to the mean.
//  - Bucket width 4096 (16 KiB LDS) -> 245 buckets -> ONE block owns a whole
//    bucket: accumulate via ds_add, then compute violations straight from LDS
//    and reduce. Deletes the 8-replica rep buffer (-32MB W, -36MB R, -1 kernel).
//  - Phase-1 chunk 4096 -> 8192 (1024 thr x VPT 8): halves block count ->
//    halves cursor atomics and run-boundary write-allocate fetches.
// Proven invariants kept: NT loads on streams (r3 win), PLAIN stores on bins
// (r3 NT-store regression), fp16 L2-resident gather (r3 win).
// ---------------------------------------------------------------------------

#define BW_LOG2 12
#define BW (1 << BW_LOG2)            // 4096 constraints/bucket = 16 KiB LDS
#define MAXNB 256
#define P1_THREADS 1024
#define VPT 8
#define P1_CHUNK (P1_THREADS * VPT)  // 8192 nnz per phase-1 block
#define CUR_PAD 16                   // one 64B line per cursor counter

typedef int   v4i __attribute__((ext_vector_type(4)));
typedef float v4f __attribute__((ext_vector_type(4)));

__global__ void sigmoid_kernel(const float* __restrict__ pred,
                               __half* __restrict__ values, int n) {
    int i = blockIdx.x * blockDim.x + threadIdx.x;
    int stride = gridDim.x * blockDim.x;
    int n4 = n >> 2;
    const v4f* p4 = (const v4f*)pred;
    uint2* o = (uint2*)values;  // 4 halves = 8B
    for (int j = i; j < n4; j += stride) {
        v4f p = p4[j];
        float a0 = 1.0f / (1.0f + __expf(-p.x));
        float a1 = 1.0f / (1.0f + __expf(-p.y));
        float a2 = 1.0f / (1.0f + __expf(-p.z));
        float a3 = 1.0f / (1.0f + __expf(-p.w));
        unsigned lo = ((unsigned)__half_as_ushort(__float2half_rn(a1)) << 16) |
                      (unsigned)__half_as_ushort(__float2half_rn(a0));
        unsigned hi = ((unsigned)__half_as_ushort(__float2half_rn(a3)) << 16) |
                      (unsigned)__half_as_ushort(__float2half_rn(a2));
        o[j] = make_uint2(lo, hi);
    }
    for (int j = (n4 << 2) + i; j < n; j += stride)
        values[j] = __float2half_rn(1.0f / (1.0f + __expf(-pred[j])));
}

// ---------------- phase 1: bin {local cidx, fp16 val} into bucket regions ---
__global__ __launch_bounds__(P1_THREADS) void binning_kernel(
    const int* __restrict__ cidx, const int* __restrict__ vidx,
    const float* __restrict__ coeff, const __half* __restrict__ values,
    unsigned* __restrict__ bins, int* __restrict__ cursor,
    float* __restrict__ ovf, int nnz, int nb, int cap) {
    __shared__ int hist[MAXNB];
    __shared__ int sbase[MAXNB];
    const int tid = threadIdx.x;
    const long long start = (long long)blockIdx.x * P1_CHUNK;

    for (int i = tid; i < nb; i += P1_THREADS) hist[i] = 0;
    __syncthreads();

    int   cc[VPT];   // constraint index (-1 = invalid/tail)
    float vv[VPT];   // coeff * value
    int   ll[VPT];   // local offset within this block's bucket run

    if (start + P1_CHUNK <= (long long)nnz) {
        const v4i* c4 = (const v4i*)(cidx + start);
        const v4i* v4 = (const v4i*)(vidx + start);
        const v4f* w4 = (const v4f*)(coeff + start);
#pragma unroll
        for (int k = 0; k < VPT / 4; ++k) {
            int g = k * P1_THREADS + tid;
            v4i c = __builtin_nontemporal_load(&c4[g]);
            v4i v = __builtin_nontemporal_load(&v4[g]);
            v4f w = __builtin_nontemporal_load(&w4[g]);
            vv[k * 4 + 0] = w.x * __half2float(values[v.x]);
            vv[k * 4 + 1] = w.y * __half2float(values[v.y]);
            vv[k * 4 + 2] = w.z * __half2float(values[v.z]);
            vv[k * 4 + 3] = w.w * __half2float(values[v.w]);
            cc[k * 4 + 0] = c.x; cc[k * 4 + 1] = c.y;
            cc[k * 4 + 2] = c.z; cc[k * 4 + 3] = c.w;
            ll[k * 4 + 0] = atomicAdd(&hist[c.x >> BW_LOG2], 1);
            ll[k * 4 + 1] = atomicAdd(&hist[c.y >> BW_LOG2], 1);
            ll[k * 4 + 2] = atomicAdd(&hist[c.z >> BW_LOG2], 1);
            ll[k * 4 + 3] = atomicAdd(&hist[c.w >> BW_LOG2], 1);
        }
    } else {
        // guarded scalar tail block
#pragma unroll
        for (int k = 0; k < VPT; ++k) {
            long long idx = start + (long long)k * P1_THREADS + tid;
            if (idx < nnz) {
                int c = cidx[idx];
                cc[k] = c;
                vv[k] = coeff[idx] * __half2float(values[vidx[idx]]);
                ll[k] = atomicAdd(&hist[c >> BW_LOG2], 1);
            } else {
                cc[k] = -1;
            }
        }
    }
    __syncthreads();
    for (int i = tid; i < nb; i += P1_THREADS)
        sbase[i] = atomicAdd(&cursor[i * CUR_PAD], hist[i]);
    __syncthreads();
#pragma unroll
    for (int k = 0; k < VPT; ++k) {
        int c = cc[k];
        if (c < 0) continue;
        int b = c >> BW_LOG2;
        int pos = sbase[b] + ll[k];
        if (pos < cap) {
            unsigned short hb = __half_as_ushort(__float2half_rn(vv[k]));
            // PLAIN store: per-block bucket runs are contiguous; L2 merges
            // them into full lines (NT store here was the round-3 regression).
            bins[(size_t)b * cap + pos] =
                ((unsigned)hb << 16) | (unsigned)(c & (BW - 1));
        } else {
            atomicAdd(&ovf[c], vv[k]);  // never taken for uniform inputs
        }
    }
}

// --------- phase 2 (fused): accumulate bucket in LDS + violations + mean ----
__global__ __launch_bounds__(1024) void accum_viol_kernel(
    const unsigned* __restrict__ bins, const int* __restrict__ cursor,
    const float* __restrict__ ovf, const float* __restrict__ rhs,
    const int* __restrict__ sense, float* __restrict__ out,
    int cap, int n_constrs, float inv_n) {
    __shared__ float acc[BW];  // 16 KiB
    const int tid = threadIdx.x;
    const int b = blockIdx.x;

#pragma unroll
    for (int k = 0; k < BW / 1024; ++k) acc[k * 1024 + tid] = 0.0f;
    __syncthreads();

    int cnt = cursor[b * CUR_PAD];
    if (cnt > cap) cnt = cap;
    const unsigned* mb = bins + (size_t)b * cap;

    int i = tid;
    for (; i + 1024 * 3 < cnt; i += 1024 * 4) {
        unsigned e0 = __builtin_nontemporal_load(&mb[i]);
        unsigned e1 = __builtin_nontemporal_load(&mb[i + 1024]);
        unsigned e2 = __builtin_nontemporal_load(&mb[i + 2048]);
        unsigned e3 = __builtin_nontemporal_load(&mb[i + 3072]);
        atomicAdd(&acc[e0 & (BW - 1)],
                  __half2float(__ushort_as_half((unsigned short)(e0 >> 16))));
        atomicAdd(&acc[e1 & (BW - 1)],
                  __half2float(__ushort_as_half((unsigned short)(e1 >> 16))));
        atomicAdd(&acc[e2 & (BW - 1)],
                  __half2float(__ushort_as_half((unsigned short)(e2 >> 16))));
        atomicAdd(&acc[e3 & (BW - 1)],
                  __half2float(__ushort_as_half((unsigned short)(e3 >> 16))));
    }
    for (; i < cnt; i += 1024) {
        unsigned e = __builtin_nontemporal_load(&mb[i]);
        atomicAdd(&acc[e & (BW - 1)],
                  __half2float(__ushort_as_half((unsigned short)(e >> 16))));
    }
    __syncthreads();

    const int cbase = b << BW_LOG2;
    float sum = 0.0f;
#pragma unroll
    for (int k = 0; k < BW / 1024; ++k) {
        int j = k * 1024 + tid;
        int c = cbase + j;
        if (c < n_constrs) {
            float a = acc[j] + ovf[c];
            float d = a - rhs[c];
            int s = sense[c];
            sum += (s == 1) ? fmaxf(d, 0.0f)
                 : (s == 2) ? fmaxf(-d, 0.0f)
                 : (s == 3) ? fabsf(d) : 0.0f;
        }
    }

    for (int off = 32; off > 0; off >>= 1)
        sum += __shfl_down(sum, off, 64);

    __shared__ float lds[16];  // 1024 threads / 64
    int lane = tid & 63;
    int wave = tid >> 6;
    if (lane == 0) lds[wave] = sum;
    __syncthreads();
    if (wave == 0) {
        float v = (lane < 16) ? lds[lane] : 0.0f;
        for (int off = 8; off > 0; off >>= 1)
            v += __shfl_down(v, off, 64);
        if (lane == 0) atomicAdd(out, v * inv_n);
    }
}

// ---------------- fallback (small workspace): atomic scatter ----------------
__global__ void scatter_kernel(const int* __restrict__ cidx,
                               const int* __restrict__ vidx,
                               const float* __restrict__ coeff,
                               const __half* __restrict__ values,
                               float* __restrict__ ax, int nnz) {
    int i = blockIdx.x * blockDim.x + threadIdx.x;
    int stride = gridDim.x * blockDim.x;
    int n4 = nnz >> 2;
    const int4* c4 = (const int4*)cidx;
    const int4* v4 = (const int4*)vidx;
    const float4* w4 = (const float4*)coeff;
    for (int j = i; j < n4; j += stride) {
        int4 c = c4[j];
        int4 v = v4[j];
        float4 w = w4[j];
        atomicAdd(&ax[c.x], w.x * __half2float(values[v.x]));
        atomicAdd(&ax[c.y], w.y * __half2float(values[v.y]));
        atomicAdd(&ax[c.z], w.z * __half2float(values[v.z]));
        atomicAdd(&ax[c.w], w.w * __half2float(values[v.w]));
    }
    for (int j = (n4 << 2) + i; j < nnz; j += stride)
        atomicAdd(&ax[cidx[j]], coeff[j] * __half2float(values[vidx[j]]));
}

__global__ void violation_reduce_kernel(const float* __restrict__ ax,
                                        const float* __restrict__ rhs,
                                        const int* __restrict__ sense,
                                        float* __restrict__ out,
                                        int n, float inv_n) {
    int i = blockIdx.x * blockDim.x + threadIdx.x;
    int stride = gridDim.x * blockDim.x;
    float acc = 0.0f;
    for (int j = i; j < n; j += stride) {
        float d = ax[j] - rhs[j];
        int s = sense[j];
        acc += (s == 1) ? fmaxf(d, 0.0f) : (s == 2) ? fmaxf(-d, 0.0f)
             : (s == 3) ? fabsf(d) : 0.0f;
    }
    for (int off = 32; off > 0; off >>= 1)
        acc += __shfl_down(acc, off, 64);
    __shared__ float lds[8];
    int lane = threadIdx.x & 63;
    int wave = threadIdx.x >> 6;
    if (lane == 0) lds[wave] = acc;
    __syncthreads();
    if (wave == 0) {
        int nwaves = blockDim.x >> 6;
        float b = (lane < nwaves) ? lds[lane] : 0.0f;
        for (int off = 4; off > 0; off >>= 1)
            b += __shfl_down(b, off, 64);
        if (lane == 0) atomicAdd(out, b * inv_n);
    }
}

extern "C" void kernel_launch(void* const* d_in, const int* in_sizes, int n_in,
                              void* d_out, int out_size, void* d_ws, size_t ws_size,
                              hipStream_t stream) {
    const float* pred  = (const float*)d_in[0];
    const int*   cidx  = (const int*)d_in[1];
    const int*   vidx  = (const int*)d_in[2];
    const float* coeff = (const float*)d_in[3];
    const float* rhs   = (const float*)d_in[4];
    const int*   sense = (const int*)d_in[5];

    const int n_vars    = in_sizes[0];
    const int nnz       = in_sizes[1];
    const int n_constrs = in_sizes[4];

    const size_t vh_bytes = ((size_t)n_vars * 2 + 255) & ~(size_t)255;
    const size_t ovf_bytes = (((size_t)n_constrs * 4) + 255) & ~(size_t)255;

    __half* values = (__half*)d_ws;
    float* ovf = (float*)((char*)d_ws + vh_bytes);       // n_constrs (also fallback ax)
    int* cursor = (int*)((char*)ovf + ovf_bytes);        // MAXNB * CUR_PAD ints
    unsigned* bins = (unsigned*)(cursor + MAXNB * CUR_PAD);

    const int nb = (n_constrs + BW - 1) >> BW_LOG2;
    long long cap_ll = (long long)nnz / (nb > 0 ? nb : 1)
                     + (long long)nnz / ((long long)(nb > 0 ? nb : 1) * 16) + 4096;
    const int cap = (int)cap_ll;
    const size_t need = vh_bytes + ovf_bytes
                      + (size_t)MAXNB * CUR_PAD * 4
                      + (size_t)nb * (size_t)cap * 4;
    const bool fast = (nb >= 1) && (nb <= MAXNB) && (n_constrs <= (1 << 20)) &&
                      (nnz > 0) && (ws_size >= need);

    hipMemsetAsync(d_out, 0, sizeof(float), stream);

    {
        int threads = 256;
        int work = n_vars >> 2;
        int blocks = (work + threads - 1) / threads;
        if (blocks < 1) blocks = 1;
        if (blocks > 2048) blocks = 2048;
        sigmoid_kernel<<<blocks, threads, 0, stream>>>(pred, values, n_vars);
    }

    if (fast) {
        hipMemsetAsync(cursor, 0, (size_t)MAXNB * CUR_PAD * sizeof(int), stream);
        hipMemsetAsync(ovf, 0, (size_t)n_constrs * sizeof(float), stream);

        int p1_blocks = (int)(((long long)nnz + P1_CHUNK - 1) / P1_CHUNK);
        binning_kernel<<<p1_blocks, P1_THREADS, 0, stream>>>(
            cidx, vidx, coeff, values, bins, cursor, ovf, nnz, nb, cap);

        accum_viol_kernel<<<nb, 1024, 0, stream>>>(
            bins, cursor, ovf, rhs, sense, (float*)d_out,
            cap, n_constrs, 1.0f / (float)n_constrs);
    } else {
        hipMemsetAsync(ovf, 0, (size_t)n_constrs * sizeof(float), stream);
        int threads = 256;
        int work = nnz >> 2;
        int blocks = (work + threads - 1) / threads;
        if (blocks < 1) blocks = 1;
        if (blocks > 8192) blocks = 8192;
        scatter_kernel<<<blocks, threads, 0, stream>>>(
            cidx, vidx, coeff, values, ovf, nnz);

        int vthreads = 256;
        int vblocks = (n_constrs + vthreads - 1) / vthreads;
        if (vblocks > 4096) vblocks = 4096;
        violation_reduce_kernel<<<vblocks, vthreads, 0, stream>>>(
            ovf, rhs, sense, (float*)d_out, n_constrs,
            1.0f / (float)n_constrs);
    }
}